// Round 1
// baseline (1596.422 us; speedup 1.0000x reference)
//
#include <hip/hip_runtime.h>
#include <hip/hip_bf16.h>

#define HID 64
#define NGRAPHS 64

// ---------------------------------------------------------------------------
// Kernel 0: detect whether edge_index / batch are int64 or int32 on device.
// Samples the FIRST HALF of each buffer read as int64 (always in-bounds for
// either dtype). If data is int32, an int64 read combines two random indices
// -> astronomically unlikely to stay in [0, N). flags[0]=edge is 64-bit,
// flags[1]=batch is 64-bit.
// ---------------------------------------------------------------------------
__global__ __launch_bounds__(64) void detect_kernel(const void* edge, const void* batch,
                                                    int* flags, int E2, int N, int G) {
    int lane = threadIdx.x;  // 64 lanes
    // edge check: sample int64 reads within first half
    int half = E2 / 2;
    int stride = half / 64; if (stride < 1) stride = 1;
    int j = lane * stride; if (j >= half) j = half - 1;
    long long v = ((const long long*)edge)[j];
    bool ok = (v >= 0 && v < (long long)N);
    unsigned long long m = __ballot(ok);
    if (lane == 0) flags[0] = (m == ~0ULL) ? 1 : 0;
    // batch check
    int halfB = N / 2;
    int strideB = halfB / 64; if (strideB < 1) strideB = 1;
    int jb = lane * strideB; if (jb >= halfB) jb = halfB - 1;
    long long vb = ((const long long*)batch)[jb];
    bool okb = (vb >= 0 && vb < (long long)G);
    unsigned long long mb = __ballot(okb);
    if (lane == 0) flags[1] = (mb == ~0ULL) ? 1 : 0;
}

// Convert edge_index (2E elems) and batch (N elems) to int32 in workspace.
__global__ __launch_bounds__(256) void convert_kernel(const void* edge, const void* batch,
                                                      const int* __restrict__ flags,
                                                      int* __restrict__ edge32,
                                                      int* __restrict__ batch32,
                                                      int E2, int N) {
    int gid = blockIdx.x * blockDim.x + threadIdx.x;
    int isE64 = flags[0], isB64 = flags[1];
    if (gid < E2) {
        edge32[gid] = isE64 ? (int)((const long long*)edge)[gid]
                            : ((const int*)edge)[gid];
    }
    int b = gid - E2;
    if (b >= 0 && b < N) {
        batch32[b] = isB64 ? (int)((const long long*)batch)[b]
                           : ((const int*)batch)[b];
    }
}

// ---------------------------------------------------------------------------
// Layer 1 edge aggregation (features are scalar): agg1[dst] += x[src]; cnt[dst]++
// cnt (in-degree) is reused by layers 2 and 3.
// ---------------------------------------------------------------------------
__global__ __launch_bounds__(256) void edge_agg1_kernel(const int* __restrict__ src,
                                                        const int* __restrict__ dst,
                                                        const float* __restrict__ x,
                                                        float* __restrict__ agg1,
                                                        int* __restrict__ cnt, int E) {
    int e = blockIdx.x * blockDim.x + threadIdx.x;
    if (e >= E) return;
    int s = src[e], d = dst[e];
    atomicAdd(&agg1[d], x[s]);
    atomicAdd(&cnt[d], 1);
}

// Layer 1 node transform: h1[i][f] = relu(mean_i*W1l[f] + b1[f] + x_i*W1r[f]) + x_i
__global__ __launch_bounds__(256) void node1_kernel(const float* __restrict__ x,
                                                    const float* __restrict__ agg1,
                                                    const int* __restrict__ cnt,
                                                    const float* __restrict__ W1l,
                                                    const float* __restrict__ b1,
                                                    const float* __restrict__ W1r,
                                                    float* __restrict__ h1, int N) {
    int tid = blockIdx.x * blockDim.x + threadIdx.x;
    if (tid >= N * HID) return;
    int i = tid >> 6, f = tid & 63;
    float c = fmaxf((float)cnt[i], 1.0f);
    float mean = agg1[i] / c;
    float xv = x[i];
    float v = mean * W1l[f] + b1[f] + xv * W1r[f];
    v = v > 0.0f ? v : 0.0f;
    h1[tid] = v + xv;
}

// ---------------------------------------------------------------------------
// Layers 2/3 edge aggregation: 16 threads per edge, each thread one float4.
// agg[dst][:] += h[src][:]
// ---------------------------------------------------------------------------
__global__ __launch_bounds__(256) void edge_agg_kernel(const int* __restrict__ src,
                                                       const int* __restrict__ dst,
                                                       const float* __restrict__ h,
                                                       float* __restrict__ agg, int E) {
    int gid = blockIdx.x * blockDim.x + threadIdx.x;
    if (gid >= E * 16) return;
    int e = gid >> 4, q = gid & 15;
    int s = src[e], d = dst[e];
    const float4 v = ((const float4*)(h + (size_t)s * HID))[q];
    float* a = agg + (size_t)d * HID + q * 4;
    atomicAdd(a + 0, v.x);
    atomicAdd(a + 1, v.y);
    atomicAdd(a + 2, v.z);
    atomicAdd(a + 3, v.w);
}

// ---------------------------------------------------------------------------
// Layers 2/3 node transform. Weights staged in LDS; 4 nodes per block pass;
// grid-stride so the 32 KB weight load amortizes over many node groups.
// hout[i][f] = relu( sum_k mean[i][k]*Wl[k][f] + hprev[i][k]*Wr[k][f] + b[f] ) + hprev[i][f]
// ---------------------------------------------------------------------------
__global__ __launch_bounds__(256) void node_layer_kernel(const float* __restrict__ hprev,
                                                         const float* __restrict__ agg,
                                                         const int* __restrict__ cnt,
                                                         const float* __restrict__ Wl,
                                                         const float* __restrict__ bvec,
                                                         const float* __restrict__ Wr,
                                                         float* __restrict__ hout, int N) {
    __shared__ float sWl[HID * HID];
    __shared__ float sWr[HID * HID];
    __shared__ float sMean[4][HID];
    __shared__ float sHp[4][HID];
    for (int idx = threadIdx.x; idx < HID * HID; idx += 256) {
        sWl[idx] = Wl[idx];
        sWr[idx] = Wr[idx];
    }
    __syncthreads();
    int f = threadIdx.x & 63;
    int sub = threadIdx.x >> 6;  // 0..3
    float bf = bvec[f];
    int ngroups = (N + 3) >> 2;
    for (int grp = blockIdx.x; grp < ngroups; grp += gridDim.x) {
        int i = grp * 4 + sub;
        if (i < N) {
            float c = fmaxf((float)cnt[i], 1.0f);
            sMean[sub][f] = agg[(size_t)i * HID + f] / c;
            sHp[sub][f] = hprev[(size_t)i * HID + f];
        }
        __syncthreads();
        if (i < N) {
            float acc = bf;
#pragma unroll
            for (int k = 0; k < HID; ++k) {
                acc += sMean[sub][k] * sWl[k * HID + f] + sHp[sub][k] * sWr[k * HID + f];
            }
            float r = acc > 0.0f ? acc : 0.0f;
            hout[(size_t)i * HID + f] = r + sHp[sub][f];
        }
        __syncthreads();
    }
}

// ---------------------------------------------------------------------------
// Global mean pool: batch is sorted, so each wave accumulates a run of nodes
// in registers and flushes one atomic per (graph-change, feature).
// ---------------------------------------------------------------------------
__global__ __launch_bounds__(256) void pool_kernel(const float* __restrict__ h,
                                                   const int* __restrict__ batch,
                                                   float* __restrict__ psum,
                                                   int* __restrict__ gcnt,
                                                   int N, int nodesPerWave) {
    int wave = (blockIdx.x * blockDim.x + threadIdx.x) >> 6;
    int f = threadIdx.x & 63;
    int start = wave * nodesPerWave;
    if (start >= N) return;
    int end = start + nodesPerWave;
    if (end > N) end = N;
    int g = batch[start];
    float acc = 0.0f;
    int c = 0;
    for (int i = start; i < end; ++i) {
        int gi = batch[i];
        if (gi != g) {
            atomicAdd(&psum[g * HID + f], acc);
            if (f == 0) atomicAdd(&gcnt[g], c);
            acc = 0.0f; c = 0; g = gi;
        }
        acc += h[(size_t)i * HID + f];
        c++;
    }
    atomicAdd(&psum[g * HID + f], acc);
    if (f == 0) atomicAdd(&gcnt[g], c);
}

// ---------------------------------------------------------------------------
// FC head: one block (64 threads) per graph.
// out[g] = relu(mean_g @ Wfc1 + bfc1) @ Wfc2 + bfc2
// ---------------------------------------------------------------------------
__global__ __launch_bounds__(64) void fc_kernel(const float* __restrict__ psum,
                                                const int* __restrict__ gcnt,
                                                const float* __restrict__ Wfc1,
                                                const float* __restrict__ bfc1,
                                                const float* __restrict__ Wfc2,
                                                const float* __restrict__ bfc2,
                                                float* __restrict__ out) {
    int g = blockIdx.x;
    int t = threadIdx.x;
    __shared__ float mean[HID];
    float c = fmaxf((float)gcnt[g], 1.0f);
    mean[t] = psum[g * HID + t] / c;
    __syncthreads();
    float v = 0.0f;
    if (t < 32) {
        float acc = bfc1[t];
#pragma unroll
        for (int k = 0; k < HID; ++k) acc += mean[k] * Wfc1[k * 32 + t];
        float hcc = acc > 0.0f ? acc : 0.0f;
        v = hcc * Wfc2[t];
    }
#pragma unroll
    for (int off = 32; off >= 1; off >>= 1) v += __shfl_down(v, off);
    if (t == 0) out[g] = v + bfc2[0];
}

extern "C" void kernel_launch(void* const* d_in, const int* in_sizes, int n_in,
                              void* d_out, int out_size, void* d_ws, size_t ws_size,
                              hipStream_t stream) {
    const int N = in_sizes[0];       // 50000
    const int E2 = in_sizes[1];      // 2*E
    const int E = E2 / 2;

    const float* x    = (const float*)d_in[0];
    const void*  edge = d_in[1];
    const void*  batch= d_in[2];
    const float* W1l  = (const float*)d_in[3];
    const float* b1   = (const float*)d_in[4];
    const float* W1r  = (const float*)d_in[5];
    const float* W2l  = (const float*)d_in[6];
    const float* b2   = (const float*)d_in[7];
    const float* W2r  = (const float*)d_in[8];
    const float* W3l  = (const float*)d_in[9];
    const float* b3   = (const float*)d_in[10];
    const float* W3r  = (const float*)d_in[11];
    const float* Wfc1 = (const float*)d_in[12];
    const float* bfc1 = (const float*)d_in[13];
    const float* Wfc2 = (const float*)d_in[14];
    const float* bfc2 = (const float*)d_in[15];
    float* out = (float*)d_out;

    // Workspace layout (all 16B aligned; N*4 = 200000 bytes, 16-divisible)
    char* ws = (char*)d_ws;
    size_t o = 0;
    int*   cnt     = (int*)(ws + o);   o += (size_t)N * 4;            // in-degree
    float* agg1    = (float*)(ws + o); o += (size_t)N * 4;            // layer1 scalar agg
    float* h1      = (float*)(ws + o); o += (size_t)N * HID * 4;      // also reused as h3
    float* agg     = (float*)(ws + o); o += (size_t)N * HID * 4;      // layer2/3 agg
    float* h2      = (float*)(ws + o); o += (size_t)N * HID * 4;
    float* psum    = (float*)(ws + o); o += (size_t)NGRAPHS * HID * 4;
    int*   gcnt    = (int*)(ws + o);   o += (size_t)NGRAPHS * 4;
    int*   flags   = (int*)(ws + o);   o += 16;
    int*   edge32  = (int*)(ws + o);   o += (size_t)E2 * 4;
    int*   batch32 = (int*)(ws + o);   o += (size_t)N * 4;
    float* h3 = h1;  // h1 dead after layer-2 node transform

    const int* src = edge32;
    const int* dst = edge32 + E;

    // Zero accumulators (ws is poisoned 0xAA before every call)
    hipMemsetAsync(cnt, 0, (size_t)N * 8, stream);                       // cnt + agg1
    hipMemsetAsync(agg, 0, (size_t)N * HID * 4, stream);
    hipMemsetAsync(psum, 0, (size_t)NGRAPHS * HID * 4 + NGRAPHS * 4, stream);  // psum + gcnt

    // Index dtype detection + conversion to int32
    detect_kernel<<<1, 64, 0, stream>>>(edge, batch, flags, E2, N, NGRAPHS);
    {
        int total = E2 + N;
        convert_kernel<<<(total + 255) / 256, 256, 0, stream>>>(edge, batch, flags,
                                                                edge32, batch32, E2, N);
    }

    // Layer 1
    edge_agg1_kernel<<<(E + 255) / 256, 256, 0, stream>>>(src, dst, x, agg1, cnt, E);
    node1_kernel<<<((size_t)N * HID + 255) / 256, 256, 0, stream>>>(x, agg1, cnt,
                                                                    W1l, b1, W1r, h1, N);

    // Layer 2
    edge_agg_kernel<<<((size_t)E * 16 + 255) / 256, 256, 0, stream>>>(src, dst, h1, agg, E);
    node_layer_kernel<<<1024, 256, 0, stream>>>(h1, agg, cnt, W2l, b2, W2r, h2, N);

    // Layer 3 (reuse agg buffer)
    hipMemsetAsync(agg, 0, (size_t)N * HID * 4, stream);
    edge_agg_kernel<<<((size_t)E * 16 + 255) / 256, 256, 0, stream>>>(src, dst, h2, agg, E);
    node_layer_kernel<<<1024, 256, 0, stream>>>(h2, agg, cnt, W3l, b3, W3r, h3, N);

    // Pool + FC head
    {
        int nodesPerWave = 64;
        int waves = (N + nodesPerWave - 1) / nodesPerWave;
        int threads = waves * 64;
        pool_kernel<<<(threads + 255) / 256, 256, 0, stream>>>(h3, batch32, psum, gcnt,
                                                               N, nodesPerWave);
    }
    fc_kernel<<<NGRAPHS, 64, 0, stream>>>(psum, gcnt, Wfc1, bfc1, Wfc2, bfc2, out);
}

// Round 2
// 506.391 us; speedup vs baseline: 3.1525x; 3.1525x over previous
//
#include <hip/hip_runtime.h>
#include <hip/hip_bf16.h>

#define HID 64
#define NGRAPHS 64
#define SCAN_T 1024

// ---------------------------------------------------------------------------
// Detect whether edge_index / batch are int64 or int32 on device.
// Samples int64 reads within the first half of each buffer (in-bounds for
// either dtype). int32 data read as int64 pairs random indices -> virtually
// never all in [0, range). flags[0]=edge is 64-bit, flags[1]=batch is 64-bit.
// ---------------------------------------------------------------------------
__global__ __launch_bounds__(64) void detect_kernel(const void* edge, const void* batch,
                                                    int* flags, int E2, int N, int G) {
    int lane = threadIdx.x;
    int half = E2 / 2;
    int stride = half / 64; if (stride < 1) stride = 1;
    int j = lane * stride; if (j >= half) j = half - 1;
    long long v = ((const long long*)edge)[j];
    bool ok = (v >= 0 && v < (long long)N);
    unsigned long long m = __ballot(ok);
    if (lane == 0) flags[0] = (m == ~0ULL) ? 1 : 0;
    int halfB = N / 2;
    int strideB = halfB / 64; if (strideB < 1) strideB = 1;
    int jb = lane * strideB; if (jb >= halfB) jb = halfB - 1;
    long long vb = ((const long long*)batch)[jb];
    bool okb = (vb >= 0 && vb < (long long)G);
    unsigned long long mb = __ballot(okb);
    if (lane == 0) flags[1] = (mb == ~0ULL) ? 1 : 0;
}

__device__ __forceinline__ int idx_at(const void* p, int i, bool is64) {
    return is64 ? (int)((const long long*)p)[i] : ((const int*)p)[i];
}

// ---------------------------------------------------------------------------
// CSR build step 1: in-degree counts (int atomics on 50K counters).
// ---------------------------------------------------------------------------
__global__ __launch_bounds__(256) void count_kernel(const void* edge, const int* __restrict__ flags,
                                                    int* __restrict__ cnt, int E) {
    int e = blockIdx.x * blockDim.x + threadIdx.x;
    if (e >= E) return;
    bool is64 = flags[0] != 0;
    int d = idx_at(edge, E + e, is64);
    atomicAdd(&cnt[d], 1);
}

// ---------------------------------------------------------------------------
// CSR build step 2: exclusive scan of cnt -> rowptr[N+1], plus cursor copy.
// Single block of 1024 threads, ~49 elements each + LDS Hillis-Steele scan.
// ---------------------------------------------------------------------------
__global__ __launch_bounds__(SCAN_T) void scan_kernel(const int* __restrict__ cnt,
                                                      int* __restrict__ rowptr,
                                                      int* __restrict__ cursor, int N) {
    __shared__ int s[SCAN_T];
    int t = threadIdx.x;
    int chunk = (N + SCAN_T - 1) / SCAN_T;
    int lo = t * chunk;
    int hi = lo + chunk; if (hi > N) hi = N;
    int sum = 0;
    for (int i = lo; i < hi; ++i) sum += cnt[i];
    s[t] = sum;
    __syncthreads();
    for (int off = 1; off < SCAN_T; off <<= 1) {
        int tmp = (t >= off) ? s[t - off] : 0;
        __syncthreads();
        s[t] += tmp;
        __syncthreads();
    }
    int run = (t == 0) ? 0 : s[t - 1];
    for (int i = lo; i < hi; ++i) {
        rowptr[i] = run;
        cursor[i] = run;
        run += cnt[i];
    }
    if (t == SCAN_T - 1) rowptr[N] = s[SCAN_T - 1];
}

// ---------------------------------------------------------------------------
// CSR build step 3: scatter src indices into csr_src by destination.
// ---------------------------------------------------------------------------
__global__ __launch_bounds__(256) void scatter_kernel(const void* edge, const int* __restrict__ flags,
                                                      int* __restrict__ cursor,
                                                      int* __restrict__ csr_src, int E) {
    int e = blockIdx.x * blockDim.x + threadIdx.x;
    if (e >= E) return;
    bool is64 = flags[0] != 0;
    int srcv = idx_at(edge, e, is64);
    int d = idx_at(edge, E + e, is64);
    int pos = atomicAdd(&cursor[d], 1);
    csr_src[pos] = srcv;
}

// ---------------------------------------------------------------------------
// Layer 1 aggregation (scalar feature): gather mean of x over neighbors.
// ---------------------------------------------------------------------------
__global__ __launch_bounds__(256) void gather1_kernel(const int* __restrict__ rowptr,
                                                      const int* __restrict__ csr,
                                                      const float* __restrict__ x,
                                                      float* __restrict__ mean1, int N) {
    int i = blockIdx.x * blockDim.x + threadIdx.x;
    if (i >= N) return;
    int r0 = rowptr[i], r1 = rowptr[i + 1];
    float s = 0.0f;
    for (int j = r0; j < r1; ++j) s += x[csr[j]];
    mean1[i] = (r1 > r0) ? s / (float)(r1 - r0) : 0.0f;
}

// Layer 1 node transform: h1[i][f] = relu(mean1_i*W1l[f] + b1[f] + x_i*W1r[f]) + x_i
__global__ __launch_bounds__(256) void node1_kernel(const float* __restrict__ x,
                                                    const float* __restrict__ mean1,
                                                    const float* __restrict__ W1l,
                                                    const float* __restrict__ b1,
                                                    const float* __restrict__ W1r,
                                                    float* __restrict__ h1, int N) {
    int tid = blockIdx.x * blockDim.x + threadIdx.x;
    if (tid >= N * HID) return;
    int i = tid >> 6, f = tid & 63;
    float xv = x[i];
    float v = mean1[i] * W1l[f] + b1[f] + xv * W1r[f];
    v = v > 0.0f ? v : 0.0f;
    h1[tid] = v + xv;
}

// ---------------------------------------------------------------------------
// Layers 2/3 aggregation via gather: 16 lanes per node, float4 per lane.
// Writes the MEAN row directly (degree = rowptr diff). No atomics.
// ---------------------------------------------------------------------------
__global__ __launch_bounds__(256) void gather_mean_kernel(const int* __restrict__ rowptr,
                                                          const int* __restrict__ csr,
                                                          const float* __restrict__ h,
                                                          float* __restrict__ mean, int N) {
    int grp = threadIdx.x >> 4;      // 16 groups per block
    int l = threadIdx.x & 15;        // lane within group -> one float4 of the row
    int i = blockIdx.x * 16 + grp;
    if (i >= N) return;
    int r0 = rowptr[i], r1 = rowptr[i + 1];
    float4 acc = make_float4(0.f, 0.f, 0.f, 0.f);
    for (int j = r0; j < r1; ++j) {
        int s = csr[j];
        const float4 v = *(const float4*)(h + (size_t)s * HID + l * 4);
        acc.x += v.x; acc.y += v.y; acc.z += v.z; acc.w += v.w;
    }
    float inv = (r1 > r0) ? 1.0f / (float)(r1 - r0) : 0.0f;
    acc.x *= inv; acc.y *= inv; acc.z *= inv; acc.w *= inv;
    *(float4*)(mean + (size_t)i * HID + l * 4) = acc;
}

// ---------------------------------------------------------------------------
// Layers 2/3 node transform. Weights staged in LDS; 4 nodes per block pass.
// hout[i][f] = relu( sum_k mean[i][k]*Wl[k][f] + hprev[i][k]*Wr[k][f] + b[f] ) + hprev[i][f]
// ---------------------------------------------------------------------------
__global__ __launch_bounds__(256) void node_layer_kernel(const float* __restrict__ hprev,
                                                         const float* __restrict__ mean,
                                                         const float* __restrict__ Wl,
                                                         const float* __restrict__ bvec,
                                                         const float* __restrict__ Wr,
                                                         float* __restrict__ hout, int N) {
    __shared__ float sWl[HID * HID];
    __shared__ float sWr[HID * HID];
    __shared__ float sMean[4][HID];
    __shared__ float sHp[4][HID];
    for (int idx = threadIdx.x; idx < HID * HID; idx += 256) {
        sWl[idx] = Wl[idx];
        sWr[idx] = Wr[idx];
    }
    __syncthreads();
    int f = threadIdx.x & 63;
    int sub = threadIdx.x >> 6;  // 0..3
    float bf = bvec[f];
    int ngroups = (N + 3) >> 2;
    for (int grp = blockIdx.x; grp < ngroups; grp += gridDim.x) {
        int i = grp * 4 + sub;
        if (i < N) {
            sMean[sub][f] = mean[(size_t)i * HID + f];
            sHp[sub][f] = hprev[(size_t)i * HID + f];
        }
        __syncthreads();
        if (i < N) {
            float acc = bf;
#pragma unroll
            for (int k = 0; k < HID; ++k) {
                acc += sMean[sub][k] * sWl[k * HID + f] + sHp[sub][k] * sWr[k * HID + f];
            }
            float r = acc > 0.0f ? acc : 0.0f;
            hout[(size_t)i * HID + f] = r + sHp[sub][f];
        }
        __syncthreads();
    }
}

// ---------------------------------------------------------------------------
// Global mean pool: batch is sorted -> run-length accumulate per wave.
// ---------------------------------------------------------------------------
__global__ __launch_bounds__(256) void pool_kernel(const float* __restrict__ h,
                                                   const void* batch,
                                                   const int* __restrict__ flags,
                                                   float* __restrict__ psum,
                                                   int* __restrict__ gcnt,
                                                   int N, int nodesPerWave) {
    int wave = (blockIdx.x * blockDim.x + threadIdx.x) >> 6;
    int f = threadIdx.x & 63;
    int start = wave * nodesPerWave;
    if (start >= N) return;
    bool is64 = flags[1] != 0;
    int end = start + nodesPerWave;
    if (end > N) end = N;
    int g = idx_at(batch, start, is64);
    float acc = 0.0f;
    int c = 0;
    for (int i = start; i < end; ++i) {
        int gi = idx_at(batch, i, is64);
        if (gi != g) {
            atomicAdd(&psum[g * HID + f], acc);
            if (f == 0) atomicAdd(&gcnt[g], c);
            acc = 0.0f; c = 0; g = gi;
        }
        acc += h[(size_t)i * HID + f];
        c++;
    }
    atomicAdd(&psum[g * HID + f], acc);
    if (f == 0) atomicAdd(&gcnt[g], c);
}

// ---------------------------------------------------------------------------
// FC head: one block (64 threads) per graph.
// ---------------------------------------------------------------------------
__global__ __launch_bounds__(64) void fc_kernel(const float* __restrict__ psum,
                                                const int* __restrict__ gcnt,
                                                const float* __restrict__ Wfc1,
                                                const float* __restrict__ bfc1,
                                                const float* __restrict__ Wfc2,
                                                const float* __restrict__ bfc2,
                                                float* __restrict__ out) {
    int g = blockIdx.x;
    int t = threadIdx.x;
    __shared__ float mean[HID];
    float c = fmaxf((float)gcnt[g], 1.0f);
    mean[t] = psum[g * HID + t] / c;
    __syncthreads();
    float v = 0.0f;
    if (t < 32) {
        float acc = bfc1[t];
#pragma unroll
        for (int k = 0; k < HID; ++k) acc += mean[k] * Wfc1[k * 32 + t];
        float hcc = acc > 0.0f ? acc : 0.0f;
        v = hcc * Wfc2[t];
    }
#pragma unroll
    for (int off = 32; off >= 1; off >>= 1) v += __shfl_down(v, off);
    if (t == 0) out[g] = v + bfc2[0];
}

extern "C" void kernel_launch(void* const* d_in, const int* in_sizes, int n_in,
                              void* d_out, int out_size, void* d_ws, size_t ws_size,
                              hipStream_t stream) {
    const int N = in_sizes[0];       // 50000
    const int E2 = in_sizes[1];      // 2*E
    const int E = E2 / 2;

    const float* x    = (const float*)d_in[0];
    const void*  edge = d_in[1];
    const void*  batch= d_in[2];
    const float* W1l  = (const float*)d_in[3];
    const float* b1   = (const float*)d_in[4];
    const float* W1r  = (const float*)d_in[5];
    const float* W2l  = (const float*)d_in[6];
    const float* b2   = (const float*)d_in[7];
    const float* W2r  = (const float*)d_in[8];
    const float* W3l  = (const float*)d_in[9];
    const float* b3   = (const float*)d_in[10];
    const float* W3r  = (const float*)d_in[11];
    const float* Wfc1 = (const float*)d_in[12];
    const float* bfc1 = (const float*)d_in[13];
    const float* Wfc2 = (const float*)d_in[14];
    const float* bfc2 = (const float*)d_in[15];
    float* out = (float*)d_out;

    // Workspace layout
    char* ws = (char*)d_ws;
    size_t o = 0;
    int*   cnt     = (int*)(ws + o);   o += (size_t)N * 4;        // degree counts (dead after scan)
    int*   rowptr  = (int*)(ws + o);   o += ((size_t)N + 4) * 4;  // CSR row pointers
    int*   cursor  = (int*)(ws + o);   o += (size_t)N * 4;        // scatter cursors (dead after scatter)
    int*   csr     = (int*)(ws + o);   o += (size_t)E * 4;        // CSR src indices
    float* h1      = (float*)(ws + o); o += (size_t)N * HID * 4;  // reused as h3
    float* meanb   = (float*)(ws + o); o += (size_t)N * HID * 4;  // mean buffer, layers 2/3
    float* h2      = (float*)(ws + o); o += (size_t)N * HID * 4;
    float* psum    = (float*)(ws + o); o += (size_t)NGRAPHS * HID * 4;
    int*   gcnt    = (int*)(ws + o);   o += (size_t)NGRAPHS * 4;
    int*   flags   = (int*)(ws + o);   o += 16;
    float* mean1   = (float*)cnt;      // alias: cnt dead before mean1 written
    float* h3 = h1;                    // h1 dead after layer-2 node transform

    // Zero what must be zero (ws is poisoned 0xAA before every call)
    hipMemsetAsync(cnt, 0, (size_t)N * 4, stream);
    hipMemsetAsync(psum, 0, (size_t)NGRAPHS * HID * 4 + NGRAPHS * 4, stream);

    // Index dtype detection
    detect_kernel<<<1, 64, 0, stream>>>(edge, batch, flags, E2, N, NGRAPHS);

    // CSR build: count -> scan -> scatter
    count_kernel<<<(E + 255) / 256, 256, 0, stream>>>(edge, flags, cnt, E);
    scan_kernel<<<1, SCAN_T, 0, stream>>>(cnt, rowptr, cursor, N);
    scatter_kernel<<<(E + 255) / 256, 256, 0, stream>>>(edge, flags, cursor, csr, E);

    // Layer 1
    gather1_kernel<<<(N + 255) / 256, 256, 0, stream>>>(rowptr, csr, x, mean1, N);
    node1_kernel<<<((size_t)N * HID + 255) / 256, 256, 0, stream>>>(x, mean1, W1l, b1, W1r, h1, N);

    // Layer 2
    gather_mean_kernel<<<(N + 15) / 16, 256, 0, stream>>>(rowptr, csr, h1, meanb, N);
    node_layer_kernel<<<1024, 256, 0, stream>>>(h1, meanb, W2l, b2, W2r, h2, N);

    // Layer 3
    gather_mean_kernel<<<(N + 15) / 16, 256, 0, stream>>>(rowptr, csr, h2, meanb, N);
    node_layer_kernel<<<1024, 256, 0, stream>>>(h2, meanb, W3l, b3, W3r, h3, N);

    // Pool + FC head
    {
        int nodesPerWave = 64;
        int waves = (N + nodesPerWave - 1) / nodesPerWave;
        int threads = waves * 64;
        pool_kernel<<<(threads + 255) / 256, 256, 0, stream>>>(h3, batch, flags, psum, gcnt,
                                                               N, nodesPerWave);
    }
    fc_kernel<<<NGRAPHS, 64, 0, stream>>>(psum, gcnt, Wfc1, bfc1, Wfc2, bfc2, out);
}

// Round 3
// 405.970 us; speedup vs baseline: 3.9324x; 1.2474x over previous
//
#include <hip/hip_runtime.h>
#include <hip/hip_bf16.h>

#define HID 64
#define NGRAPHS 64
#define SCAN_B 256   // elements per scan block

// ---------------------------------------------------------------------------
// Detect whether edge_index / batch are int64 or int32 on device.
// Samples int64 reads within the first half of each buffer (in-bounds for
// either dtype). int32 data read as int64 pairs random indices -> virtually
// never all in [0, range). flags[0]=edge is 64-bit, flags[1]=batch is 64-bit.
// ---------------------------------------------------------------------------
__global__ __launch_bounds__(64) void detect_kernel(const void* edge, const void* batch,
                                                    int* flags, int E2, int N, int G) {
    int lane = threadIdx.x;
    int half = E2 / 2;
    int stride = half / 64; if (stride < 1) stride = 1;
    int j = lane * stride; if (j >= half) j = half - 1;
    long long v = ((const long long*)edge)[j];
    bool ok = (v >= 0 && v < (long long)N);
    unsigned long long m = __ballot(ok);
    if (lane == 0) flags[0] = (m == ~0ULL) ? 1 : 0;
    int halfB = N / 2;
    int strideB = halfB / 64; if (strideB < 1) strideB = 1;
    int jb = lane * strideB; if (jb >= halfB) jb = halfB - 1;
    long long vb = ((const long long*)batch)[jb];
    bool okb = (vb >= 0 && vb < (long long)G);
    unsigned long long mb = __ballot(okb);
    if (lane == 0) flags[1] = (mb == ~0ULL) ? 1 : 0;
}

__device__ __forceinline__ int idx_at(const void* p, int i, bool is64) {
    return is64 ? (int)((const long long*)p)[i] : ((const int*)p)[i];
}

// ---------------------------------------------------------------------------
// CSR build step 1: in-degree counts (int atomics on 50K counters).
// ---------------------------------------------------------------------------
__global__ __launch_bounds__(256) void count_kernel(const void* edge, const int* __restrict__ flags,
                                                    int* __restrict__ cnt, int E) {
    int e = blockIdx.x * blockDim.x + threadIdx.x;
    if (e >= E) return;
    bool is64 = flags[0] != 0;
    int d = idx_at(edge, E + e, is64);
    atomicAdd(&cnt[d], 1);
}

// ---------------------------------------------------------------------------
// Multi-block exclusive scan of cnt[N] -> rowptr[N+1] (+cursor copy).
// Step A: per-block (256 elems) sum -> blocksum[nb]
// ---------------------------------------------------------------------------
__global__ __launch_bounds__(SCAN_B) void scan_reduce_kernel(const int* __restrict__ cnt,
                                                             int* __restrict__ blocksum, int N) {
    __shared__ int s[SCAN_B / 64];
    int i = blockIdx.x * SCAN_B + threadIdx.x;
    int v = (i < N) ? cnt[i] : 0;
#pragma unroll
    for (int off = 32; off >= 1; off >>= 1) v += __shfl_down(v, off);
    int wave = threadIdx.x >> 6;
    if ((threadIdx.x & 63) == 0) s[wave] = v;
    __syncthreads();
    if (threadIdx.x == 0) {
        int t = 0;
#pragma unroll
        for (int w = 0; w < SCAN_B / 64; ++w) t += s[w];
        blocksum[blockIdx.x] = t;
    }
}

// Step B: single block scans blocksums (nb <= 256) -> blockoff (exclusive),
// and writes the grand total to rowptr[N].
__global__ __launch_bounds__(SCAN_B) void scan_top_kernel(const int* __restrict__ blocksum,
                                                          int* __restrict__ blockoff,
                                                          int* __restrict__ rowptr,
                                                          int nb, int N) {
    __shared__ int s[SCAN_B];
    int t = threadIdx.x;
    int v = (t < nb) ? blocksum[t] : 0;
    s[t] = v;
    __syncthreads();
#pragma unroll
    for (int off = 1; off < SCAN_B; off <<= 1) {
        int tmp = (t >= off) ? s[t - off] : 0;
        __syncthreads();
        s[t] += tmp;
        __syncthreads();
    }
    if (t < nb) blockoff[t] = s[t] - v;   // exclusive
    if (t == SCAN_B - 1) rowptr[N] = s[SCAN_B - 1];
}

// Step C: per-block exclusive scan + block offset -> rowptr, cursor.
__global__ __launch_bounds__(SCAN_B) void scan_apply_kernel(const int* __restrict__ cnt,
                                                            const int* __restrict__ blockoff,
                                                            int* __restrict__ rowptr,
                                                            int* __restrict__ cursor, int N) {
    __shared__ int s[SCAN_B];
    int t = threadIdx.x;
    int i = blockIdx.x * SCAN_B + t;
    int v = (i < N) ? cnt[i] : 0;
    s[t] = v;
    __syncthreads();
#pragma unroll
    for (int off = 1; off < SCAN_B; off <<= 1) {
        int tmp = (t >= off) ? s[t - off] : 0;
        __syncthreads();
        s[t] += tmp;
        __syncthreads();
    }
    if (i < N) {
        int r = blockoff[blockIdx.x] + s[t] - v;  // exclusive
        rowptr[i] = r;
        cursor[i] = r;
    }
}

// ---------------------------------------------------------------------------
// CSR build step 3: scatter src indices into csr_src by destination.
// ---------------------------------------------------------------------------
__global__ __launch_bounds__(256) void scatter_kernel(const void* edge, const int* __restrict__ flags,
                                                      int* __restrict__ cursor,
                                                      int* __restrict__ csr_src, int E) {
    int e = blockIdx.x * blockDim.x + threadIdx.x;
    if (e >= E) return;
    bool is64 = flags[0] != 0;
    int srcv = idx_at(edge, e, is64);
    int d = idx_at(edge, E + e, is64);
    int pos = atomicAdd(&cursor[d], 1);
    csr_src[pos] = srcv;
}

// ---------------------------------------------------------------------------
// Layer 1 aggregation (scalar feature): gather mean of x over neighbors.
// ---------------------------------------------------------------------------
__global__ __launch_bounds__(256) void gather1_kernel(const int* __restrict__ rowptr,
                                                      const int* __restrict__ csr,
                                                      const float* __restrict__ x,
                                                      float* __restrict__ mean1, int N) {
    int i = blockIdx.x * blockDim.x + threadIdx.x;
    if (i >= N) return;
    int r0 = rowptr[i], r1 = rowptr[i + 1];
    float s = 0.0f;
    for (int j = r0; j < r1; ++j) s += x[csr[j]];
    mean1[i] = (r1 > r0) ? s / (float)(r1 - r0) : 0.0f;
}

// Layer 1 node transform: h1[i][f] = relu(mean1_i*W1l[f] + b1[f] + x_i*W1r[f]) + x_i
__global__ __launch_bounds__(256) void node1_kernel(const float* __restrict__ x,
                                                    const float* __restrict__ mean1,
                                                    const float* __restrict__ W1l,
                                                    const float* __restrict__ b1,
                                                    const float* __restrict__ W1r,
                                                    float* __restrict__ h1, int N) {
    int tid = blockIdx.x * blockDim.x + threadIdx.x;
    if (tid >= N * HID) return;
    int i = tid >> 6, f = tid & 63;
    float xv = x[i];
    float v = mean1[i] * W1l[f] + b1[f] + xv * W1r[f];
    v = v > 0.0f ? v : 0.0f;
    h1[tid] = v + xv;
}

// ---------------------------------------------------------------------------
// Layers 2/3 aggregation via gather: 16 lanes per node, float4 per lane.
// Writes the MEAN row directly (degree = rowptr diff). No atomics.
// ---------------------------------------------------------------------------
__global__ __launch_bounds__(256) void gather_mean_kernel(const int* __restrict__ rowptr,
                                                          const int* __restrict__ csr,
                                                          const float* __restrict__ h,
                                                          float* __restrict__ mean, int N) {
    int grp = threadIdx.x >> 4;      // 16 groups per block
    int l = threadIdx.x & 15;        // lane within group -> one float4 of the row
    int i = blockIdx.x * 16 + grp;
    if (i >= N) return;
    int r0 = rowptr[i], r1 = rowptr[i + 1];
    float4 acc = make_float4(0.f, 0.f, 0.f, 0.f);
    for (int j = r0; j < r1; ++j) {
        int s = csr[j];
        const float4 v = *(const float4*)(h + (size_t)s * HID + l * 4);
        acc.x += v.x; acc.y += v.y; acc.z += v.z; acc.w += v.w;
    }
    float inv = (r1 > r0) ? 1.0f / (float)(r1 - r0) : 0.0f;
    acc.x *= inv; acc.y *= inv; acc.z *= inv; acc.w *= inv;
    *(float4*)(mean + (size_t)i * HID + l * 4) = acc;
}

// ---------------------------------------------------------------------------
// Layers 2/3 node transform. Weights staged in LDS; 4 nodes per block pass.
// hout[i][f] = relu( sum_k mean[i][k]*Wl[k][f] + hprev[i][k]*Wr[k][f] + b[f] ) + hprev[i][f]
// ---------------------------------------------------------------------------
__global__ __launch_bounds__(256) void node_layer_kernel(const float* __restrict__ hprev,
                                                         const float* __restrict__ mean,
                                                         const float* __restrict__ Wl,
                                                         const float* __restrict__ bvec,
                                                         const float* __restrict__ Wr,
                                                         float* __restrict__ hout, int N) {
    __shared__ float sWl[HID * HID];
    __shared__ float sWr[HID * HID];
    __shared__ float sMean[4][HID];
    __shared__ float sHp[4][HID];
    for (int idx = threadIdx.x; idx < HID * HID; idx += 256) {
        sWl[idx] = Wl[idx];
        sWr[idx] = Wr[idx];
    }
    __syncthreads();
    int f = threadIdx.x & 63;
    int sub = threadIdx.x >> 6;  // 0..3
    float bf = bvec[f];
    int ngroups = (N + 3) >> 2;
    for (int grp = blockIdx.x; grp < ngroups; grp += gridDim.x) {
        int i = grp * 4 + sub;
        if (i < N) {
            sMean[sub][f] = mean[(size_t)i * HID + f];
            sHp[sub][f] = hprev[(size_t)i * HID + f];
        }
        __syncthreads();
        if (i < N) {
            float acc = bf;
#pragma unroll
            for (int k = 0; k < HID; ++k) {
                acc += sMean[sub][k] * sWl[k * HID + f] + sHp[sub][k] * sWr[k * HID + f];
            }
            float r = acc > 0.0f ? acc : 0.0f;
            hout[(size_t)i * HID + f] = r + sHp[sub][f];
        }
        __syncthreads();
    }
}

// ---------------------------------------------------------------------------
// Global mean pool: batch is sorted -> run-length accumulate per wave.
// ---------------------------------------------------------------------------
__global__ __launch_bounds__(256) void pool_kernel(const float* __restrict__ h,
                                                   const void* batch,
                                                   const int* __restrict__ flags,
                                                   float* __restrict__ psum,
                                                   int* __restrict__ gcnt,
                                                   int N, int nodesPerWave) {
    int wave = (blockIdx.x * blockDim.x + threadIdx.x) >> 6;
    int f = threadIdx.x & 63;
    int start = wave * nodesPerWave;
    if (start >= N) return;
    bool is64 = flags[1] != 0;
    int end = start + nodesPerWave;
    if (end > N) end = N;
    int g = idx_at(batch, start, is64);
    float acc = 0.0f;
    int c = 0;
    for (int i = start; i < end; ++i) {
        int gi = idx_at(batch, i, is64);
        if (gi != g) {
            atomicAdd(&psum[g * HID + f], acc);
            if (f == 0) atomicAdd(&gcnt[g], c);
            acc = 0.0f; c = 0; g = gi;
        }
        acc += h[(size_t)i * HID + f];
        c++;
    }
    atomicAdd(&psum[g * HID + f], acc);
    if (f == 0) atomicAdd(&gcnt[g], c);
}

// ---------------------------------------------------------------------------
// FC head: one block (64 threads) per graph.
// ---------------------------------------------------------------------------
__global__ __launch_bounds__(64) void fc_kernel(const float* __restrict__ psum,
                                                const int* __restrict__ gcnt,
                                                const float* __restrict__ Wfc1,
                                                const float* __restrict__ bfc1,
                                                const float* __restrict__ Wfc2,
                                                const float* __restrict__ bfc2,
                                                float* __restrict__ out) {
    int g = blockIdx.x;
    int t = threadIdx.x;
    __shared__ float mean[HID];
    float c = fmaxf((float)gcnt[g], 1.0f);
    mean[t] = psum[g * HID + t] / c;
    __syncthreads();
    float v = 0.0f;
    if (t < 32) {
        float acc = bfc1[t];
#pragma unroll
        for (int k = 0; k < HID; ++k) acc += mean[k] * Wfc1[k * 32 + t];
        float hcc = acc > 0.0f ? acc : 0.0f;
        v = hcc * Wfc2[t];
    }
#pragma unroll
    for (int off = 32; off >= 1; off >>= 1) v += __shfl_down(v, off);
    if (t == 0) out[g] = v + bfc2[0];
}

extern "C" void kernel_launch(void* const* d_in, const int* in_sizes, int n_in,
                              void* d_out, int out_size, void* d_ws, size_t ws_size,
                              hipStream_t stream) {
    const int N = in_sizes[0];       // 50000
    const int E2 = in_sizes[1];      // 2*E
    const int E = E2 / 2;

    const float* x    = (const float*)d_in[0];
    const void*  edge = d_in[1];
    const void*  batch= d_in[2];
    const float* W1l  = (const float*)d_in[3];
    const float* b1   = (const float*)d_in[4];
    const float* W1r  = (const float*)d_in[5];
    const float* W2l  = (const float*)d_in[6];
    const float* b2   = (const float*)d_in[7];
    const float* W2r  = (const float*)d_in[8];
    const float* W3l  = (const float*)d_in[9];
    const float* b3   = (const float*)d_in[10];
    const float* W3r  = (const float*)d_in[11];
    const float* Wfc1 = (const float*)d_in[12];
    const float* bfc1 = (const float*)d_in[13];
    const float* Wfc2 = (const float*)d_in[14];
    const float* bfc2 = (const float*)d_in[15];
    float* out = (float*)d_out;

    const int nb = (N + SCAN_B - 1) / SCAN_B;   // scan blocks (196 for N=50000)

    // Workspace layout
    char* ws = (char*)d_ws;
    size_t o = 0;
    int*   cnt     = (int*)(ws + o);   o += (size_t)N * 4;        // degree counts
    int*   rowptr  = (int*)(ws + o);   o += ((size_t)N + 4) * 4;  // CSR row pointers
    int*   cursor  = (int*)(ws + o);   o += (size_t)N * 4;        // scatter cursors
    int*   csr     = (int*)(ws + o);   o += (size_t)E * 4;        // CSR src indices
    float* h1      = (float*)(ws + o); o += (size_t)N * HID * 4;  // reused as h3
    float* meanb   = (float*)(ws + o); o += (size_t)N * HID * 4;  // mean buffer, layers 2/3
    float* h2      = (float*)(ws + o); o += (size_t)N * HID * 4;
    float* psum    = (float*)(ws + o); o += (size_t)NGRAPHS * HID * 4;
    int*   gcnt    = (int*)(ws + o);   o += (size_t)NGRAPHS * 4;
    int*   flags   = (int*)(ws + o);   o += 16;
    int*   blocksum= (int*)(ws + o);   o += (size_t)SCAN_B * 4;
    int*   blockoff= (int*)(ws + o);   o += (size_t)SCAN_B * 4;
    float* mean1   = (float*)cnt;      // alias: cnt dead before mean1 written
    float* h3 = h1;                    // h1 dead after layer-2 node transform

    // Zero what must be zero (ws is poisoned 0xAA before every call)
    hipMemsetAsync(cnt, 0, (size_t)N * 4, stream);
    hipMemsetAsync(psum, 0, (size_t)NGRAPHS * HID * 4 + NGRAPHS * 4, stream);

    // Index dtype detection
    detect_kernel<<<1, 64, 0, stream>>>(edge, batch, flags, E2, N, NGRAPHS);

    // CSR build: count -> multi-block scan -> scatter
    count_kernel<<<(E + 255) / 256, 256, 0, stream>>>(edge, flags, cnt, E);
    scan_reduce_kernel<<<nb, SCAN_B, 0, stream>>>(cnt, blocksum, N);
    scan_top_kernel<<<1, SCAN_B, 0, stream>>>(blocksum, blockoff, rowptr, nb, N);
    scan_apply_kernel<<<nb, SCAN_B, 0, stream>>>(cnt, blockoff, rowptr, cursor, N);
    scatter_kernel<<<(E + 255) / 256, 256, 0, stream>>>(edge, flags, cursor, csr, E);

    // Layer 1
    gather1_kernel<<<(N + 255) / 256, 256, 0, stream>>>(rowptr, csr, x, mean1, N);
    node1_kernel<<<((size_t)N * HID + 255) / 256, 256, 0, stream>>>(x, mean1, W1l, b1, W1r, h1, N);

    // Layer 2
    gather_mean_kernel<<<(N + 15) / 16, 256, 0, stream>>>(rowptr, csr, h1, meanb, N);
    node_layer_kernel<<<1024, 256, 0, stream>>>(h1, meanb, W2l, b2, W2r, h2, N);

    // Layer 3
    gather_mean_kernel<<<(N + 15) / 16, 256, 0, stream>>>(rowptr, csr, h2, meanb, N);
    node_layer_kernel<<<1024, 256, 0, stream>>>(h2, meanb, W3l, b3, W3r, h3, N);

    // Pool + FC head
    {
        int nodesPerWave = 64;
        int waves = (N + nodesPerWave - 1) / nodesPerWave;
        int threads = waves * 64;
        pool_kernel<<<(threads + 255) / 256, 256, 0, stream>>>(h3, batch, flags, psum, gcnt,
                                                               N, nodesPerWave);
    }
    fc_kernel<<<NGRAPHS, 64, 0, stream>>>(psum, gcnt, Wfc1, bfc1, Wfc2, bfc2, out);
}